// Round 18
// baseline (1539.103 us; speedup 1.0000x reference)
//
#include <hip/hip_runtime.h>
#include <math.h>

#define NN 104960      // nodes = 205 * 512
#define OUT 200
#define EMB 101
#define NPG 205
#define BATCH 512
#define NE 629760      // edges
#define LAYERS 6

typedef _Float16 h8 __attribute__((ext_vector_type(8)));
typedef float f4 __attribute__((ext_vector_type(4)));

// fast transcendentals on native v_exp_f32 / v_rcp_f32
__device__ __forceinline__ float fsig(float x) {
  return __builtin_amdgcn_rcpf(1.f + __builtin_amdgcn_exp2f(-1.44269504f*x));
}
__device__ __forceinline__ float ftanh(float x) {
  float e = __builtin_amdgcn_exp2f(2.88539008f*x);      // e^(2x)
  return 1.f - 2.f*__builtin_amdgcn_rcpf(e + 1.f);
}

// ---------------- utility kernels ----------------
__global__ void zero_i32(int* p, int n){ int i=blockIdx.x*256+threadIdx.x; if(i<n) p[i]=0; }
__global__ void zero_f32(float* p, int n){ int i=blockIdx.x*blockDim.x+threadIdx.x; if(i<n) p[i]=0.f; }

// h[N,200] fp16 = pad(x[N,101])
__global__ void pad16(const float* __restrict__ x, _Float16* __restrict__ h) {
  int idx = blockIdx.x*256 + threadIdx.x;
  if (idx >= NN*OUT) return;
  int n = idx / OUT, j = idx - n*OUT;
  h[idx] = (j < EMB) ? (_Float16)x[n*EMB + j] : (_Float16)0.f;
}

// Wf[i][k][o] = sum_j ggc_w[i][k][j] * wih[o][j]   (i<6, k<200, o<600)  fp32
__global__ void fuse_w_kernel(const float* __restrict__ ggc_w, const float* __restrict__ wih,
                              float* __restrict__ Wf) {
  long idx = (long)blockIdx.x*256 + threadIdx.x;
  if (idx >= 6L*200*600) return;
  int o = (int)(idx % 600); long r = idx / 600; int k = (int)(r % 200); int i = (int)(r / 200);
  const float* wr = ggc_w + ((long)i*200 + k)*200;
  const float* vr = wih + (long)o*200;
  float acc = 0.f;
  for (int j=0;j<200;j++) acc += wr[j]*vr[j];
  Wf[idx] = acc;
}

// Bp[layer][gate][s(7)][j(208)][k(32)] fp16 — 16-wide fragment order for 16x16x32 MFMA.
__global__ void pack_b(const float* __restrict__ Wf, const float* __restrict__ whh,
                       _Float16* __restrict__ Bp) {
  size_t idx = (size_t)blockIdx.x*256 + threadIdx.x;
  if (idx >= 6UL*6*7*208*32) return;
  int kk = (int)(idx & 31); size_t r = idx >> 5;
  int j = (int)(r % 208); r /= 208;
  int s = (int)(r % 7);   r /= 7;
  int g = (int)(r % 6);   int l = (int)(r / 6);
  int k = s*32 + kk;
  float v = 0.f;
  if (k < 200 && j < 200) {
    v = (g < 3) ? Wf[(size_t)l*120000 + (size_t)k*600 + g*200 + j]
                : whh[((size_t)(g-3)*200 + j)*200 + k];
  }
  Bp[idx] = (_Float16)v;
}

// conv1 weights -> fragment order Wp[s(21)][o(64)][kk(32)] fp16
__global__ void pack_w1(const float* __restrict__ w, _Float16* __restrict__ Wp) {
  int idx = blockIdx.x*256 + threadIdx.x;   // 21*64*32 = 43008
  if (idx >= 21*64*32) return;
  int kk = idx & 31; int r = idx >> 5;
  int o = r & 63; int s = r >> 6;
  int kc = s/7, p = (s%7)*32 + kk;
  float v = 0.f;
  if (o < 50 && p < 205) v = w[o*615 + p*3 + kc];
  Wp[idx] = (_Float16)v;
}

// ---------------- CSR build ----------------
__global__ void count_deg(const int* __restrict__ ei, int* __restrict__ cnt) {
  int e = blockIdx.x*256+threadIdx.x;
  if (e < NE) atomicAdd(&cnt[ei[NE + e]], 1);
}

// hierarchical scan: NN = 205 blocks x 512
__global__ __launch_bounds__(512) void scan_block(const int* __restrict__ cnt,
        int* __restrict__ partial, int* __restrict__ bsum) {
  __shared__ int sd[512];
  int gi = blockIdx.x*512 + threadIdx.x;
  int v = cnt[gi];
  sd[threadIdx.x] = v;
  __syncthreads();
  #pragma unroll
  for (int d=1; d<512; d<<=1) {
    int t = (threadIdx.x>=d)? sd[threadIdx.x-d] : 0;
    __syncthreads();
    sd[threadIdx.x] += t;
    __syncthreads();
  }
  partial[gi] = sd[threadIdx.x] - v;              // exclusive within block
  if (threadIdx.x==511) bsum[blockIdx.x] = sd[511];
}

__global__ __launch_bounds__(256) void scan_bsum(int* __restrict__ bsum, int nb) {
  __shared__ int sd[256];
  int v = (threadIdx.x<nb)? bsum[threadIdx.x] : 0;
  sd[threadIdx.x] = v;
  __syncthreads();
  #pragma unroll
  for (int d=1; d<256; d<<=1) {
    int t = (threadIdx.x>=d)? sd[threadIdx.x-d] : 0;
    __syncthreads();
    sd[threadIdx.x] += t;
    __syncthreads();
  }
  if (threadIdx.x<nb) bsum[threadIdx.x] = sd[threadIdx.x] - v;   // exclusive
}

__global__ void scan_add(const int* __restrict__ partial, const int* __restrict__ bsum,
                         int* __restrict__ rowptr, int* __restrict__ cursor) {
  int i = blockIdx.x*256 + threadIdx.x;
  if (i < NN) {
    int v = partial[i] + bsum[i >> 9];
    rowptr[i] = v;
    cursor[i] = v;
  }
  if (i == 0) rowptr[NN] = NE;
}

__global__ void fill_csr(const int* __restrict__ ei, int* __restrict__ cursor, int* __restrict__ col) {
  int e = blockIdx.x*256+threadIdx.x;
  if (e < NE) {
    int dst = ei[NE+e], src = ei[e];
    int pos = atomicAdd(&cursor[dst], 1);
    col[pos] = src;
  }
}

// hagg[n,:] += h[col,:] ; thread = (node, 8-elem chunk), 25 chunks/node.
__global__ void gather16(const _Float16* __restrict__ h, const int* __restrict__ rowptr,
                         const int* __restrict__ col, _Float16* __restrict__ out) {
  int idx = blockIdx.x*256 + threadIdx.x;
  if (idx >= NN*25) return;
  int n = idx / 25, c = idx - n*25;
  int s = rowptr[n], e = rowptr[n+1];
  float a[8];
  #pragma unroll
  for (int i=0;i<8;i++) a[i]=0.f;
  if (e > s) {
    h8 v[8];
    #pragma unroll
    for (int q=0;q<8;q++) {
      int pp = s+q; if (pp >= e) pp = e-1;         // clamp: dup loads hit L1
      v[q] = *(const h8*)(h + (size_t)col[pp]*200 + c*8);
    }
    int lim = e - s; if (lim > 8) lim = 8;
    #pragma unroll
    for (int q=0;q<8;q++) {
      if (q < lim) {
        #pragma unroll
        for (int i=0;i<8;i++) a[i] += (float)v[q][i];
      }
    }
    int p = s + 8;
    for (; p+3 < e; p += 4) {
      const h8 v0 = *(const h8*)(h + (size_t)col[p]*200   + c*8);
      const h8 v1 = *(const h8*)(h + (size_t)col[p+1]*200 + c*8);
      const h8 v2 = *(const h8*)(h + (size_t)col[p+2]*200 + c*8);
      const h8 v3 = *(const h8*)(h + (size_t)col[p+3]*200 + c*8);
      #pragma unroll
      for (int i=0;i<8;i++) a[i] += ((float)v0[i] + (float)v1[i]) + ((float)v2[i] + (float)v3[i]);
    }
    for (; p < e; ++p) {
      const h8 v0 = *(const h8*)(h + (size_t)col[p]*200 + c*8);
      #pragma unroll
      for (int i=0;i<8;i++) a[i] += (float)v0[i];
    }
  }
  h8 o;
  #pragma unroll
  for (int i=0;i<8;i++) o[i] = (_Float16)a[i];
  *(h8*)(out + (size_t)n*200 + c*8) = o;
}

// ---------------- MFMA fused GRU (16x16x32, M=32, 13 waves, high occupancy) ----------------
// Block: 832 thr = 13 waves, M=32 rows. Wave w owns j-tile w (16 cols), all 6 gates,
// 2 row-subtiles (each B load feeds 2 MFMAs). acc = 48 f32/lane -> ~120 regs -> ~4 waves/SIMD.
__global__ __launch_bounds__(832) void gru_mfma16(
    const _Float16* __restrict__ hagg, const _Float16* __restrict__ h,
    const _Float16* __restrict__ Bp,
    const float* __restrict__ bih, const float* __restrict__ bhh,
    _Float16* __restrict__ hnew) {
  __shared__ _Float16 As[2][32][232];
  const int tid = threadIdx.x;
  const int bm = blockIdx.x * 32;

  for (int idx = tid; idx < 1600; idx += 832) {     // 2*32*25 h8 chunks
    int m_ = idx / 800; int rem = idx - m_*800;
    int row = rem / 25; int kc = rem - row*25;
    const _Float16* src = m_ ? h : hagg;
    *(h8*)&As[m_][row][kc*8] = *(const h8*)(src + (size_t)(bm+row)*200 + kc*8);
  }
  if (tid < 256) {                                  // zero pad k = 200..231
    int m_ = tid >> 7; int rem = tid & 127;
    int row = rem >> 2; int c = rem & 3;
    h8 z;
    #pragma unroll
    for (int i=0;i<8;i++) z[i] = (_Float16)0.f;
    *(h8*)&As[m_][row][200 + c*8] = z;
  }
  __syncthreads();

  const int lane = tid & 63;
  const int wv = tid >> 6;          // 0..12 = j-tile
  const int l15 = lane & 15;
  const int kg = lane >> 2 >> 2;    // lane>>4: 0..3

  f4 acc[2][6];
  #pragma unroll
  for (int m_=0;m_<2;m_++)
    #pragma unroll
    for (int g=0;g<6;g++) { acc[m_][g][0]=0.f; acc[m_][g][1]=0.f; acc[m_][g][2]=0.f; acc[m_][g][3]=0.f; }

  const _Float16* bbase = Bp + ((size_t)(wv*16 + l15))*32 + kg*8;
  __builtin_amdgcn_s_setprio(1);
  #pragma unroll
  for (int s=0; s<7; s++) {
    const h8 aA0 = *(const h8*)&As[0][l15][s*32 + kg*8];
    const h8 aA1 = *(const h8*)&As[0][16+l15][s*32 + kg*8];
    const h8 aH0 = *(const h8*)&As[1][l15][s*32 + kg*8];
    const h8 aH1 = *(const h8*)&As[1][16+l15][s*32 + kg*8];
    #pragma unroll
    for (int g=0; g<6; g++) {
      const h8 b = *(const h8*)(bbase + (size_t)(g*7 + s)*208*32);
      acc[0][g] = __builtin_amdgcn_mfma_f32_16x16x32_f16((g<3)?aA0:aH0, b, acc[0][g], 0,0,0);
      acc[1][g] = __builtin_amdgcn_mfma_f32_16x16x32_f16((g<3)?aA1:aH1, b, acc[1][g], 0,0,0);
    }
  }
  __builtin_amdgcn_s_setprio(0);

  // epilogue: 16x16 C layout: col=lane&15, row=(lane>>4)*4+reg
  const int j = wv*16 + l15;
  if (j < 200) {
    const float bri = bih[j],      brh = bhh[j];
    const float bzi = bih[200+j],  bzh = bhh[200+j];
    const float bni = bih[400+j],  bnh = bhh[400+j];
    #pragma unroll
    for (int m_=0;m_<2;m_++) {
      #pragma unroll
      for (int r=0;r<4;r++) {
        const int row = m_*16 + kg*4 + r;
        const float rr = fsig(acc[m_][0][r]+bri + acc[m_][3][r]+brh);
        const float zz = fsig(acc[m_][1][r]+bzi + acc[m_][4][r]+bzh);
        const float nn = ftanh(acc[m_][2][r]+bni + rr*(acc[m_][5][r]+bnh));
        const float hv = (float)As[1][row][j];
        hnew[(size_t)(bm+row)*200 + j] = (_Float16)((1.f-zz)*nn + zz*hv);
      }
    }
  }
}

// ---------------- head (fp16 storage, fp32 math; z/y branches fused per stage) ----------------
__global__ __launch_bounds__(256) void build_xt(const _Float16* __restrict__ hid,
        const float* __restrict__ x, _Float16* __restrict__ Xt) {
  __shared__ _Float16 T[32][34];
  int pt = blockIdx.x*32, lt = blockIdx.y*32, b = blockIdx.z;
  int lo = threadIdx.x & 31;
  int po = threadIdx.x >> 5;
  #pragma unroll
  for (int q=0;q<4;q++) {
    int p = pt + po + q*8;
    int l = lt + lo;
    _Float16 v = (_Float16)0.f;
    if (p < 205 && l < 301) {
      size_t node = (size_t)b*205 + p;
      v = (l < 200) ? hid[node*200 + l] : (_Float16)x[node*101 + (l-200)];
    }
    T[po + q*8][lo] = v;
  }
  __syncthreads();
  #pragma unroll
  for (int q=0;q<4;q++) {
    int l = lt + po + q*8;
    int p = pt + lo;
    if (l < 304)
      Xt[((size_t)b*304 + l)*224 + p] = T[lo][po + q*8];
  }
}

// LDS-staged conv1, z+y fused. XCD swizzle: lid = (n&7)*576 + (n>>3).
__global__ __launch_bounds__(256) void conv1_both(const _Float16* __restrict__ Xt,
        const _Float16* __restrict__ Wp, const float* __restrict__ bias,
        _Float16* __restrict__ z_out, _Float16* __restrict__ y_out) {
  __shared__ _Float16 X[66][232];
  int n = blockIdx.x;
  int lid = (n & 7)*576 + (n >> 3);
  int b = lid / 9;
  int tile = lid - b*9;
  int isY = (tile >= 5);
  int LIN = isY ? 200 : 301;
  _Float16* out = isY ? y_out : z_out;
  int t0 = (isY ? (tile-5) : tile) * 64;
  const _Float16* xb = Xt + (size_t)b*304*224;

  for (int idx = threadIdx.x; idx < 66*28; idx += 256) {
    int r = idx / 28, pc = idx - r*28;
    int tp = t0 - 1 + r;
    h8 v = {0,0,0,0,0,0,0,0};
    if (tp >= 0 && tp < LIN) v = *(const h8*)(xb + (size_t)tp*224 + pc*8);
    *(h8*)&X[r][pc*8] = v;
  }
  __syncthreads();

  int lane = threadIdx.x & 63;
  int tt = threadIdx.x >> 6;
  int j = lane & 15;
  int kg = lane >> 4;
  int t = t0 + tt*16 + j;
  f4 acc[4];
  #pragma unroll
  for (int a=0;a<4;a++) { acc[a][0]=0.f; acc[a][1]=0.f; acc[a][2]=0.f; acc[a][3]=0.f; }
  #pragma unroll
  for (int s=0; s<21; s++) {
    const int kc = s/7;
    const int p0 = (s - kc*7)*32 + kg*8;
    const int r = tt*16 + j + kc;
    const h8 bfrag = *(const h8*)&X[r][p0];
    #pragma unroll
    for (int a=0;a<4;a++) {
      const h8 afrag = *(const h8*)(Wp + ((size_t)(s*64 + a*16 + j)*32 + kg*8));
      acc[a] = __builtin_amdgcn_mfma_f32_16x16x32_f16(afrag, bfrag, acc[a], 0,0,0);
    }
  }
  if (t < LIN) {
    #pragma unroll
    for (int a=0;a<4;a++) {
      #pragma unroll
      for (int r=0;r<4;r++) {
        int o = a*16 + kg*4 + r;
        if (o < 50) out[((size_t)b*50 + o)*LIN + t] = (_Float16)(acc[a][r] + bias[o]);
      }
    }
  }
}

// grid (C, 16, 2): z==0 -> (vz,Lz,sums0) ; z==1 -> (vy,Ly,sums1)
__global__ void bn_stats2(const _Float16* __restrict__ vz, const _Float16* __restrict__ vy,
        int C, int Lz, int Ly, float* __restrict__ sums0, float* __restrict__ sums1) {
  const _Float16* v = blockIdx.z ? vy : vz;
  int L = blockIdx.z ? Ly : Lz;
  float* sums = blockIdx.z ? sums1 : sums0;
  int c = blockIdx.x;
  int bs = blockIdx.y * 32;
  float s = 0.f, s2 = 0.f;
  for (int idx = threadIdx.x; idx < 32*L; idx += 256) {
    int b = bs + idx / L, t = idx - (idx/L)*L;
    float val = (float)v[((long)b*C + c)*L + t];
    s += val; s2 += val*val;
  }
  __shared__ float rs[256], rq[256];
  rs[threadIdx.x]=s; rq[threadIdx.x]=s2; __syncthreads();
  for (int d=128; d>0; d>>=1){
    if (threadIdx.x<d){ rs[threadIdx.x]+=rs[threadIdx.x+d]; rq[threadIdx.x]+=rq[threadIdx.x+d]; }
    __syncthreads();
  }
  if (threadIdx.x==0){ atomicAdd(&sums[2*c], rs[0]); atomicAdd(&sums[2*c+1], rq[0]); }
}

// grid (maxBlocks, 1, 2): BN(finalize inlined)+LeakyReLU+maxpool for z and y in one launch
__global__ void bn_act_pool2(const _Float16* __restrict__ vz, const _Float16* __restrict__ vy,
      const float* __restrict__ sums0, const float* __restrict__ sums1,
      const float* __restrict__ g, const float* __restrict__ bb,
      float inv_nz, float inv_ny, int C, int Lz, int Ly, int Loz, int Loy,
      int K, int do_relu, _Float16* __restrict__ outz, _Float16* __restrict__ outy) {
  const _Float16* v = blockIdx.z ? vy : vz;
  const float* sums = blockIdx.z ? sums1 : sums0;
  float inv_n = blockIdx.z ? inv_ny : inv_nz;
  int Lin = blockIdx.z ? Ly : Lz;
  int Lout = blockIdx.z ? Loy : Loz;
  _Float16* out = blockIdx.z ? outy : outz;
  int idx = blockIdx.x*256 + threadIdx.x;
  int total = BATCH*C*Lout;
  if (idx>=total) return;
  int t = idx % Lout; int r = idx / Lout; int c = r % C; int b = r / C;
  float mean = sums[2*c]*inv_n;
  float var  = sums[2*c+1]*inv_n - mean*mean;
  float scl  = g[c]*rsqrtf(var + 1e-5f);
  float shf  = bb[c] - mean*scl;
  const _Float16* src = v + ((long)(b*C + c))*Lin + 2*t;
  float m = -3.4e38f;
  for (int k=0;k<K;k++){
    float u = (float)src[k]*scl + shf;
    if (do_relu) u = (u>=0.f)? u : 0.01f*u;
    m = fmaxf(m,u);
  }
  out[idx] = (_Float16)m;
}

// grid (BATCH, 2): z -> Lm=150 ; y -> Lm=99
__global__ __launch_bounds__(256) void conv2_both(const _Float16* __restrict__ inz,
        const _Float16* __restrict__ iny, const float* __restrict__ w,
        const float* __restrict__ b2, _Float16* __restrict__ outz, _Float16* __restrict__ outy) {
  __shared__ float sw[1000];
  __shared__ _Float16 sin[50*150];
  int b = blockIdx.x;
  int isY = blockIdx.y;
  int Lm = isY ? 99 : 150;
  const _Float16* in = isY ? iny : inz;
  _Float16* out = isY ? outy : outz;
  for (int i=threadIdx.x;i<1000;i+=256) sw[i]=w[i];
  for (int i=threadIdx.x;i<50*Lm;i+=256) sin[i] = in[(long)b*50*Lm + i];
  __syncthreads();
  int Lo = Lm + 2;
  for (int idx=threadIdx.x; idx<20*Lo; idx+=256) {
    int c = idx / Lo, t = idx - c*Lo;
    float acc = b2[c];
    if (t>=1 && t<=Lm) {
      const _Float16* sp = sin + (t-1);
      const float* wp = sw + c*50;
      for (int i=0;i<50;i++) acc += wp[i]*(float)sp[i*Lm];
    }
    out[(long)b*20*Lo + idx] = (_Float16)acc;
  }
}

__global__ void final_kernel(const _Float16* __restrict__ Zf, const _Float16* __restrict__ Yf,
        const float* __restrict__ fc1w, const float* __restrict__ fc1b,
        const float* __restrict__ fc2w, const float* __restrict__ fc2b, float* __restrict__ out) {
  int b = blockIdx.x;
  float s1=0.f, s2=0.f;
  for (int i=threadIdx.x;i<1520;i+=256) s1 += (float)Zf[(long)b*1520+i]*fc1w[i];
  for (int i=threadIdx.x;i<1000;i+=256) s2 += (float)Yf[(long)b*1000+i]*fc2w[i];
  __shared__ float r1[256], r2[256];
  r1[threadIdx.x]=s1; r2[threadIdx.x]=s2; __syncthreads();
  for (int d=128; d>0; d>>=1){
    if (threadIdx.x<d){ r1[threadIdx.x]+=r1[threadIdx.x+d]; r2[threadIdx.x]+=r2[threadIdx.x+d]; }
    __syncthreads();
  }
  if (threadIdx.x==0){
    float res = (r1[0]+fc1b[0])*(r2[0]+fc2b[0]);
    out[b] = fsig(res);
  }
}

// ---------------- launch ----------------
extern "C" void kernel_launch(void* const* d_in, const int* in_sizes, int n_in,
                              void* d_out, int out_size, void* d_ws, size_t ws_size,
                              hipStream_t stream) {
  const float* x    = (const float*)d_in[0];
  const int*   ei   = (const int*)d_in[1];
  const float* ggcw = (const float*)d_in[2];
  const float* wih  = (const float*)d_in[3];
  const float* whh  = (const float*)d_in[4];
  const float* bih  = (const float*)d_in[5];
  const float* bhh  = (const float*)d_in[6];
  const float* c1w  = (const float*)d_in[7];
  const float* c1b  = (const float*)d_in[8];
  const float* bn1g = (const float*)d_in[9];
  const float* bn1b = (const float*)d_in[10];
  const float* c2w  = (const float*)d_in[11];
  const float* c2b  = (const float*)d_in[12];
  const float* bn2g = (const float*)d_in[13];
  const float* bn2b = (const float*)d_in[14];
  const float* fc1w = (const float*)d_in[15];
  const float* fc1b = (const float*)d_in[16];
  const float* fc2w = (const float*)d_in[17];
  const float* fc2b = (const float*)d_in[18];
  float* out = (float*)d_out;

  char* ws = (char*)d_ws;
  size_t HS = (size_t)NN*OUT*2;                       // 41,984,000 B per h buffer
  _Float16* h0 = (_Float16*)ws;
  _Float16* h1 = (_Float16*)(ws + HS);
  _Float16* h2 = (_Float16*)(ws + 2*HS);
  _Float16* Xt = h1;                                  // overlay: 512*304*224*2 = 69.7 MB
  char* aux = ws + 3*HS;
  float*    Wf = (float*)aux;    aux += (size_t)6*200*600*4;
  _Float16* Bp = (_Float16*)aux; aux += (size_t)6*6*7*208*32*2;    // 3.35 MB
  _Float16* Wp1 = (_Float16*)aux; aux += (size_t)21*64*32*2;
  int* deg    = (int*)aux;       aux += (size_t)NN*4;
  int* part   = (int*)aux;       aux += (size_t)NN*4;
  int* bsum   = (int*)aux;       aux += 256*4;
  int* rowptr = (int*)aux;       aux += (size_t)(NN+16)*4;
  int* cursor = (int*)aux;       aux += (size_t)NN*4;
  int* col    = (int*)aux;       aux += (size_t)NE*4;
  float* sums = (float*)aux;     aux += 512*4;        // 4 buffers of 128
  _Float16* z_c1  = (_Float16*)aux;
  _Float16* y_c1  = z_c1  + (size_t)512*50*301;
  _Float16* z_mp1 = y_c1  + (size_t)512*50*200;
  _Float16* y_mp1 = z_mp1 + (size_t)512*50*150;
  _Float16* z_c2  = y_mp1 + (size_t)512*50*99;
  _Float16* y_c2  = z_c2  + (size_t)512*20*152;
  _Float16* z_mp2 = y_c2  + (size_t)512*20*101;
  _Float16* y_mp2 = z_mp2 + (size_t)512*1520;

  // precompute
  pad16<<<NN*OUT/256, 256, 0, stream>>>(x, h0);
  fuse_w_kernel<<<(6*200*600+255)/256, 256, 0, stream>>>(ggcw, wih, Wf);
  pack_b<<<6*6*7*208*32/256, 256, 0, stream>>>(Wf, whh, Bp);
  pack_w1<<<(21*64*32+255)/256, 256, 0, stream>>>(c1w, Wp1);
  zero_f32<<<2, 256, 0, stream>>>(sums, 512);         // all 4 BN sum buffers, once
  // CSR (hierarchical scan)
  zero_i32<<<(NN+255)/256, 256, 0, stream>>>(deg, NN);
  count_deg<<<NE/256, 256, 0, stream>>>(ei, deg);
  scan_block<<<NN/512, 512, 0, stream>>>(deg, part, bsum);
  scan_bsum<<<1, 256, 0, stream>>>(bsum, NN/512);
  scan_add<<<(NN+255)/256, 256, 0, stream>>>(part, bsum, rowptr, cursor);
  fill_csr<<<NE/256, 256, 0, stream>>>(ei, cursor, col);

  // GGC layers (split: gather then GRU)
  _Float16* cur = h0; _Float16* other = h2;
  for (int i=0;i<LAYERS;i++){
    gather16<<<NN*25/256, 256, 0, stream>>>(cur, rowptr, col, h1);
    gru_mfma16<<<NN/32, 832, 0, stream>>>(h1, cur, Bp + (size_t)i*6*7*208*32,
                                          bih, bhh, other);
    _Float16* t = cur; cur = other; other = t;
  }
  // cur == h0 (final hidden, fp16); h1/h2 free -> Xt overlay

  // head
  build_xt<<<dim3(7, 10, BATCH), 256, 0, stream>>>(cur, x, Xt);
  conv1_both<<<4608, 256, 0, stream>>>(Xt, Wp1, c1b, z_c1, y_c1);

  bn_stats2<<<dim3(50,16,2), 256, 0, stream>>>(z_c1, y_c1, 50, 301, 200, sums, sums+128);
  bn_act_pool2<<<dim3((512*50*150+255)/256, 1, 2), 256, 0, stream>>>(z_c1, y_c1,
      sums, sums+128, bn1g, bn1b, 1.f/(512.f*301.f), 1.f/(512.f*200.f),
      50, 301, 200, 150, 99, 3, 1, z_mp1, y_mp1);

  conv2_both<<<dim3(BATCH, 2), 256, 0, stream>>>(z_mp1, y_mp1, c2w, c2b, z_c2, y_c2);

  bn_stats2<<<dim3(20,16,2), 256, 0, stream>>>(z_c2, y_c2, 20, 152, 101, sums+256, sums+384);
  bn_act_pool2<<<dim3((512*20*76+255)/256, 1, 2), 256, 0, stream>>>(z_c2, y_c2,
      sums+256, sums+384, bn2g, bn2b, 1.f/(512.f*152.f), 1.f/(512.f*101.f),
      20, 152, 101, 76, 50, 2, 0, z_mp2, y_mp2);

  final_kernel<<<BATCH, 256, 0, stream>>>(z_mp2, y_mp2, fc1w, fc1b, fc2w, fc2b, out);
}

// Round 19
// 1342.537 us; speedup vs baseline: 1.1464x; 1.1464x over previous
//
#include <hip/hip_runtime.h>
#include <math.h>

#define NN 104960      // nodes = 205 * 512
#define OUT 200
#define EMB 101
#define NPG 205
#define BATCH 512
#define NE 629760      // edges
#define LAYERS 6

typedef _Float16 h8 __attribute__((ext_vector_type(8)));
typedef float f4 __attribute__((ext_vector_type(4)));
typedef float f16v __attribute__((ext_vector_type(16)));

// fast transcendentals on native v_exp_f32 / v_rcp_f32
__device__ __forceinline__ float fsig(float x) {
  return __builtin_amdgcn_rcpf(1.f + __builtin_amdgcn_exp2f(-1.44269504f*x));
}
__device__ __forceinline__ float ftanh(float x) {
  float e = __builtin_amdgcn_exp2f(2.88539008f*x);      // e^(2x)
  return 1.f - 2.f*__builtin_amdgcn_rcpf(e + 1.f);
}

// ---------------- utility kernels ----------------
__global__ void zero_i32(int* p, int n){ int i=blockIdx.x*256+threadIdx.x; if(i<n) p[i]=0; }
__global__ void zero_f32(float* p, int n){ int i=blockIdx.x*blockDim.x+threadIdx.x; if(i<n) p[i]=0.f; }

// h[N,200] fp16 = pad(x[N,101])
__global__ void pad16(const float* __restrict__ x, _Float16* __restrict__ h) {
  int idx = blockIdx.x*256 + threadIdx.x;
  if (idx >= NN*OUT) return;
  int n = idx / OUT, j = idx - n*OUT;
  h[idx] = (j < EMB) ? (_Float16)x[n*EMB + j] : (_Float16)0.f;
}

// Wf[i][k][o] = sum_j ggc_w[i][k][j] * wih[o][j]   (i<6, k<200, o<600)  fp32
__global__ void fuse_w_kernel(const float* __restrict__ ggc_w, const float* __restrict__ wih,
                              float* __restrict__ Wf) {
  long idx = (long)blockIdx.x*256 + threadIdx.x;
  if (idx >= 6L*200*600) return;
  int o = (int)(idx % 600); long r = idx / 600; int k = (int)(r % 200); int i = (int)(r / 200);
  const float* wr = ggc_w + ((long)i*200 + k)*200;
  const float* vr = wih + (long)o*200;
  float acc = 0.f;
  for (int j=0;j<200;j++) acc += wr[j]*vr[j];
  Wf[idx] = acc;
}

// Bp32[layer][gate][s(13)][j(224)][k(16)] fp16 — 32-wide fragment order for 32x32x16 MFMA.
__global__ void pack_b32(const float* __restrict__ Wf, const float* __restrict__ whh,
                         _Float16* __restrict__ Bp) {
  size_t idx = (size_t)blockIdx.x*256 + threadIdx.x;
  if (idx >= 6UL*6*13*224*16) return;
  int kk = (int)(idx & 15); size_t r = idx >> 4;
  int j = (int)(r % 224); r /= 224;
  int s = (int)(r % 13);  r /= 13;
  int g = (int)(r % 6);   int l = (int)(r / 6);
  int k = s*16 + kk;
  float v = 0.f;
  if (k < 200 && j < 200) {
    v = (g < 3) ? Wf[(size_t)l*120000 + (size_t)k*600 + g*200 + j]
                : whh[((size_t)(g-3)*200 + j)*200 + k];
  }
  Bp[idx] = (_Float16)v;
}

// conv1 weights -> fragment order Wp[s(21)][o(64)][kk(32)] fp16
__global__ void pack_w1(const float* __restrict__ w, _Float16* __restrict__ Wp) {
  int idx = blockIdx.x*256 + threadIdx.x;   // 21*64*32 = 43008
  if (idx >= 21*64*32) return;
  int kk = idx & 31; int r = idx >> 5;
  int o = r & 63; int s = r >> 6;
  int kc = s/7, p = (s%7)*32 + kk;
  float v = 0.f;
  if (o < 50 && p < 205) v = w[o*615 + p*3 + kc];
  Wp[idx] = (_Float16)v;
}

// ---------------- CSR build ----------------
__global__ void count_deg(const int* __restrict__ ei, int* __restrict__ cnt) {
  int e = blockIdx.x*256+threadIdx.x;
  if (e < NE) atomicAdd(&cnt[ei[NE + e]], 1);
}

// hierarchical scan: NN = 205 blocks x 512
__global__ __launch_bounds__(512) void scan_block(const int* __restrict__ cnt,
        int* __restrict__ partial, int* __restrict__ bsum) {
  __shared__ int sd[512];
  int gi = blockIdx.x*512 + threadIdx.x;
  int v = cnt[gi];
  sd[threadIdx.x] = v;
  __syncthreads();
  #pragma unroll
  for (int d=1; d<512; d<<=1) {
    int t = (threadIdx.x>=d)? sd[threadIdx.x-d] : 0;
    __syncthreads();
    sd[threadIdx.x] += t;
    __syncthreads();
  }
  partial[gi] = sd[threadIdx.x] - v;              // exclusive within block
  if (threadIdx.x==511) bsum[blockIdx.x] = sd[511];
}

__global__ __launch_bounds__(256) void scan_bsum(int* __restrict__ bsum, int nb) {
  __shared__ int sd[256];
  int v = (threadIdx.x<nb)? bsum[threadIdx.x] : 0;
  sd[threadIdx.x] = v;
  __syncthreads();
  #pragma unroll
  for (int d=1; d<256; d<<=1) {
    int t = (threadIdx.x>=d)? sd[threadIdx.x-d] : 0;
    __syncthreads();
    sd[threadIdx.x] += t;
    __syncthreads();
  }
  if (threadIdx.x<nb) bsum[threadIdx.x] = sd[threadIdx.x] - v;   // exclusive
}

__global__ void scan_add(const int* __restrict__ partial, const int* __restrict__ bsum,
                         int* __restrict__ rowptr, int* __restrict__ cursor) {
  int i = blockIdx.x*256 + threadIdx.x;
  if (i < NN) {
    int v = partial[i] + bsum[i >> 9];
    rowptr[i] = v;
    cursor[i] = v;
  }
  if (i == 0) rowptr[NN] = NE;
}

__global__ void fill_csr(const int* __restrict__ ei, int* __restrict__ cursor, int* __restrict__ col) {
  int e = blockIdx.x*256+threadIdx.x;
  if (e < NE) {
    int dst = ei[NE+e], src = ei[e];
    int pos = atomicAdd(&cursor[dst], 1);
    col[pos] = src;
  }
}

// hagg[n,:] += h[col,:] ; thread = (node, 8-elem chunk), 25 chunks/node.
__global__ void gather16(const _Float16* __restrict__ h, const int* __restrict__ rowptr,
                         const int* __restrict__ col, _Float16* __restrict__ out) {
  int idx = blockIdx.x*256 + threadIdx.x;
  if (idx >= NN*25) return;
  int n = idx / 25, c = idx - n*25;
  int s = rowptr[n], e = rowptr[n+1];
  float a[8];
  #pragma unroll
  for (int i=0;i<8;i++) a[i]=0.f;
  if (e > s) {
    h8 v[8];
    #pragma unroll
    for (int q=0;q<8;q++) {
      int pp = s+q; if (pp >= e) pp = e-1;         // clamp: dup loads hit L1
      v[q] = *(const h8*)(h + (size_t)col[pp]*200 + c*8);
    }
    int lim = e - s; if (lim > 8) lim = 8;
    #pragma unroll
    for (int q=0;q<8;q++) {
      if (q < lim) {
        #pragma unroll
        for (int i=0;i<8;i++) a[i] += (float)v[q][i];
      }
    }
    int p = s + 8;
    for (; p+3 < e; p += 4) {
      const h8 v0 = *(const h8*)(h + (size_t)col[p]*200   + c*8);
      const h8 v1 = *(const h8*)(h + (size_t)col[p+1]*200 + c*8);
      const h8 v2 = *(const h8*)(h + (size_t)col[p+2]*200 + c*8);
      const h8 v3 = *(const h8*)(h + (size_t)col[p+3]*200 + c*8);
      #pragma unroll
      for (int i=0;i<8;i++) a[i] += ((float)v0[i] + (float)v1[i]) + ((float)v2[i] + (float)v3[i]);
    }
    for (; p < e; ++p) {
      const h8 v0 = *(const h8*)(h + (size_t)col[p]*200 + c*8);
      #pragma unroll
      for (int i=0;i<8;i++) a[i] += (float)v0[i];
    }
  }
  h8 o;
  #pragma unroll
  for (int i=0;i<8;i++) o[i] = (_Float16)a[i];
  *(h8*)(out + (size_t)n*200 + c*8) = o;
}

// ---------------- MFMA fused GRU (32x32x16, M=64, B dbuf, setprio on MFMA loop) ----------------
__global__ __launch_bounds__(448) void gru_mfma2(
    const _Float16* __restrict__ hagg, const _Float16* __restrict__ h,
    const _Float16* __restrict__ Bp,
    const float* __restrict__ bih, const float* __restrict__ bhh,
    _Float16* __restrict__ hnew) {
  __shared__ _Float16 As[2][64][232];
  const int tid = threadIdx.x;
  const int bm = blockIdx.x * 64;

  for (int idx = tid; idx < 3200; idx += 448) {     // 2*64*25 h8 chunks
    int m_ = idx / 1600; int rem = idx - m_*1600;
    int row = rem / 25; int kc = rem - row*25;
    const _Float16* src = m_ ? h : hagg;
    *(h8*)&As[m_][row][kc*8] = *(const h8*)(src + (size_t)(bm+row)*200 + kc*8);
  }
  for (int idx = tid; idx < 512; idx += 448) {      // zero pad k = 200..231
    int m_ = idx / 256; int rem = idx - m_*256;
    int row = rem >> 2; int c = rem & 3;
    h8 z;
    #pragma unroll
    for (int i=0;i<8;i++) z[i] = (_Float16)0.f;
    *(h8*)&As[m_][row][200 + c*8] = z;
  }

  const int lane = tid & 63;
  const int jt = tid >> 6;          // 0..6
  const int jcol = lane & 31;
  const int kh = lane >> 5;         // k-half

  const _Float16* bbase = Bp + ((size_t)jt*32 + jcol)*16 + kh*8;
  h8 bcur[6], bnxt[6];
  #pragma unroll
  for (int g=0;g<6;g++) bcur[g] = *(const h8*)(bbase + (size_t)(g*13)*224*16);

  __syncthreads();

  f16v accL[6], accH[6];
  #pragma unroll
  for (int g=0;g<6;g++)
    #pragma unroll
    for (int r=0;r<16;r++) { accL[g][r] = 0.f; accH[g][r] = 0.f; }

  __builtin_amdgcn_s_setprio(1);
  #pragma unroll
  for (int s=0; s<13; s++) {
    if (s < 12) {
      #pragma unroll
      for (int g=0;g<6;g++) bnxt[g] = *(const h8*)(bbase + (size_t)(g*13 + s+1)*224*16);
    }
    const h8 aA0 = *(const h8*)&As[0][jcol][s*16 + kh*8];
    const h8 aA1 = *(const h8*)&As[0][32+jcol][s*16 + kh*8];
    const h8 aH0 = *(const h8*)&As[1][jcol][s*16 + kh*8];
    const h8 aH1 = *(const h8*)&As[1][32+jcol][s*16 + kh*8];
    #pragma unroll
    for (int g=0; g<6; g++) {
      accL[g] = __builtin_amdgcn_mfma_f32_32x32x16_f16((g<3)?aA0:aH0, bcur[g], accL[g], 0,0,0);
      accH[g] = __builtin_amdgcn_mfma_f32_32x32x16_f16((g<3)?aA1:aH1, bcur[g], accH[g], 0,0,0);
    }
    #pragma unroll
    for (int g=0;g<6;g++) bcur[g] = bnxt[g];
  }
  __builtin_amdgcn_s_setprio(0);

  // epilogue: C/D col=lane&31, row=(reg&3)+8*(reg>>2)+4*(lane>>5)
  const int j = jt*32 + jcol;
  if (j < 200) {
    const float bri = bih[j],      brh = bhh[j];
    const float bzi = bih[200+j],  bzh = bhh[200+j];
    const float bni = bih[400+j],  bnh = bhh[400+j];
    #pragma unroll
    for (int r=0;r<16;r++) {
      const int row = (r&3) + 8*(r>>2) + 4*kh;
      {
        const float rr = fsig(accL[0][r]+bri + accL[3][r]+brh);
        const float zz = fsig(accL[1][r]+bzi + accL[4][r]+bzh);
        const float nn = ftanh(accL[2][r]+bni + rr*(accL[5][r]+bnh));
        const float hv = (float)As[1][row][j];
        hnew[(size_t)(bm+row)*200 + j] = (_Float16)((1.f-zz)*nn + zz*hv);
      }
      {
        const float rr = fsig(accH[0][r]+bri + accH[3][r]+brh);
        const float zz = fsig(accH[1][r]+bzi + accH[4][r]+bzh);
        const float nn = ftanh(accH[2][r]+bni + rr*(accH[5][r]+bnh));
        const float hv = (float)As[1][32+row][j];
        hnew[(size_t)(bm+32+row)*200 + j] = (_Float16)((1.f-zz)*nn + zz*hv);
      }
    }
  }
}

// ---------------- head (fp16 storage, fp32 math; z/y branches fused per stage) ----------------
__global__ __launch_bounds__(256) void build_xt(const _Float16* __restrict__ hid,
        const float* __restrict__ x, _Float16* __restrict__ Xt) {
  __shared__ _Float16 T[32][34];
  int pt = blockIdx.x*32, lt = blockIdx.y*32, b = blockIdx.z;
  int lo = threadIdx.x & 31;
  int po = threadIdx.x >> 5;
  #pragma unroll
  for (int q=0;q<4;q++) {
    int p = pt + po + q*8;
    int l = lt + lo;
    _Float16 v = (_Float16)0.f;
    if (p < 205 && l < 301) {
      size_t node = (size_t)b*205 + p;
      v = (l < 200) ? hid[node*200 + l] : (_Float16)x[node*101 + (l-200)];
    }
    T[po + q*8][lo] = v;
  }
  __syncthreads();
  #pragma unroll
  for (int q=0;q<4;q++) {
    int l = lt + po + q*8;
    int p = pt + lo;
    if (l < 304)
      Xt[((size_t)b*304 + l)*224 + p] = T[lo][po + q*8];
  }
}

// LDS-staged conv1, z+y fused. XCD swizzle: lid = (n&7)*576 + (n>>3); b = lid/9, tile = lid%9.
__global__ __launch_bounds__(256) void conv1_both(const _Float16* __restrict__ Xt,
        const _Float16* __restrict__ Wp, const float* __restrict__ bias,
        _Float16* __restrict__ z_out, _Float16* __restrict__ y_out) {
  __shared__ _Float16 X[66][232];
  int n = blockIdx.x;
  int lid = (n & 7)*576 + (n >> 3);
  int b = lid / 9;
  int tile = lid - b*9;
  int isY = (tile >= 5);
  int LIN = isY ? 200 : 301;
  _Float16* out = isY ? y_out : z_out;
  int t0 = (isY ? (tile-5) : tile) * 64;
  const _Float16* xb = Xt + (size_t)b*304*224;

  // stage rows t0-1 .. t0+64 (66 rows), zero-clamped to [0, LIN)
  for (int idx = threadIdx.x; idx < 66*28; idx += 256) {
    int r = idx / 28, pc = idx - r*28;
    int tp = t0 - 1 + r;
    h8 v = {0,0,0,0,0,0,0,0};
    if (tp >= 0 && tp < LIN) v = *(const h8*)(xb + (size_t)tp*224 + pc*8);
    *(h8*)&X[r][pc*8] = v;
  }
  __syncthreads();

  int lane = threadIdx.x & 63;
  int tt = threadIdx.x >> 6;
  int j = lane & 15;
  int kg = lane >> 4;
  int t = t0 + tt*16 + j;
  f4 acc[4];
  #pragma unroll
  for (int a=0;a<4;a++) { acc[a][0]=0.f; acc[a][1]=0.f; acc[a][2]=0.f; acc[a][3]=0.f; }
  #pragma unroll
  for (int s=0; s<21; s++) {
    const int kc = s/7;
    const int p0 = (s - kc*7)*32 + kg*8;
    const int r = tt*16 + j + kc;
    const h8 bfrag = *(const h8*)&X[r][p0];
    #pragma unroll
    for (int a=0;a<4;a++) {
      const h8 afrag = *(const h8*)(Wp + ((size_t)(s*64 + a*16 + j)*32 + kg*8));
      acc[a] = __builtin_amdgcn_mfma_f32_16x16x32_f16(afrag, bfrag, acc[a], 0,0,0);
    }
  }
  if (t < LIN) {
    #pragma unroll
    for (int a=0;a<4;a++) {
      #pragma unroll
      for (int r=0;r<4;r++) {
        int o = a*16 + kg*4 + r;
        if (o < 50) out[((size_t)b*50 + o)*LIN + t] = (_Float16)(acc[a][r] + bias[o]);
      }
    }
  }
}

// grid (C, 16, 2): z==0 -> (vz,Lz,sums0) ; z==1 -> (vy,Ly,sums1)
__global__ void bn_stats2(const _Float16* __restrict__ vz, const _Float16* __restrict__ vy,
        int C, int Lz, int Ly, float* __restrict__ sums0, float* __restrict__ sums1) {
  const _Float16* v = blockIdx.z ? vy : vz;
  int L = blockIdx.z ? Ly : Lz;
  float* sums = blockIdx.z ? sums1 : sums0;
  int c = blockIdx.x;
  int bs = blockIdx.y * 32;
  float s = 0.f, s2 = 0.f;
  for (int idx = threadIdx.x; idx < 32*L; idx += 256) {
    int b = bs + idx / L, t = idx - (idx/L)*L;
    float val = (float)v[((long)b*C + c)*L + t];
    s += val; s2 += val*val;
  }
  __shared__ float rs[256], rq[256];
  rs[threadIdx.x]=s; rq[threadIdx.x]=s2; __syncthreads();
  for (int d=128; d>0; d>>=1){
    if (threadIdx.x<d){ rs[threadIdx.x]+=rs[threadIdx.x+d]; rq[threadIdx.x]+=rq[threadIdx.x+d]; }
    __syncthreads();
  }
  if (threadIdx.x==0){ atomicAdd(&sums[2*c], rs[0]); atomicAdd(&sums[2*c+1], rq[0]); }
}

// grid (maxBlocks, 1, 2): BN(finalize inlined)+LeakyReLU+maxpool for z and y in one launch
__global__ void bn_act_pool2(const _Float16* __restrict__ vz, const _Float16* __restrict__ vy,
      const float* __restrict__ sums0, const float* __restrict__ sums1,
      const float* __restrict__ g, const float* __restrict__ bb,
      float inv_nz, float inv_ny, int C, int Lz, int Ly, int Loz, int Loy,
      int K, int do_relu, _Float16* __restrict__ outz, _Float16* __restrict__ outy) {
  const _Float16* v = blockIdx.z ? vy : vz;
  const float* sums = blockIdx.z ? sums1 : sums0;
  float inv_n = blockIdx.z ? inv_ny : inv_nz;
  int Lin = blockIdx.z ? Ly : Lz;
  int Lout = blockIdx.z ? Loy : Loz;
  _Float16* out = blockIdx.z ? outy : outz;
  int idx = blockIdx.x*256 + threadIdx.x;
  int total = BATCH*C*Lout;
  if (idx>=total) return;
  int t = idx % Lout; int r = idx / Lout; int c = r % C; int b = r / C;
  float mean = sums[2*c]*inv_n;
  float var  = sums[2*c+1]*inv_n - mean*mean;
  float scl  = g[c]*rsqrtf(var + 1e-5f);
  float shf  = bb[c] - mean*scl;
  const _Float16* src = v + ((long)(b*C + c))*Lin + 2*t;
  float m = -3.4e38f;
  for (int k=0;k<K;k++){
    float u = (float)src[k]*scl + shf;
    if (do_relu) u = (u>=0.f)? u : 0.01f*u;
    m = fmaxf(m,u);
  }
  out[idx] = (_Float16)m;
}

// grid (BATCH, 2): z -> Lm=150 ; y -> Lm=99
__global__ __launch_bounds__(256) void conv2_both(const _Float16* __restrict__ inz,
        const _Float16* __restrict__ iny, const float* __restrict__ w,
        const float* __restrict__ b2, _Float16* __restrict__ outz, _Float16* __restrict__ outy) {
  __shared__ float sw[1000];
  __shared__ _Float16 sin[50*150];
  int b = blockIdx.x;
  int isY = blockIdx.y;
  int Lm = isY ? 99 : 150;
  const _Float16* in = isY ? iny : inz;
  _Float16* out = isY ? outy : outz;
  for (int i=threadIdx.x;i<1000;i+=256) sw[i]=w[i];
  for (int i=threadIdx.x;i<50*Lm;i+=256) sin[i] = in[(long)b*50*Lm + i];
  __syncthreads();
  int Lo = Lm + 2;
  for (int idx=threadIdx.x; idx<20*Lo; idx+=256) {
    int c = idx / Lo, t = idx - c*Lo;
    float acc = b2[c];
    if (t>=1 && t<=Lm) {
      const _Float16* sp = sin + (t-1);
      const float* wp = sw + c*50;
      for (int i=0;i<50;i++) acc += wp[i]*(float)sp[i*Lm];
    }
    out[(long)b*20*Lo + idx] = (_Float16)acc;
  }
}

__global__ void final_kernel(const _Float16* __restrict__ Zf, const _Float16* __restrict__ Yf,
        const float* __restrict__ fc1w, const float* __restrict__ fc1b,
        const float* __restrict__ fc2w, const float* __restrict__ fc2b, float* __restrict__ out) {
  int b = blockIdx.x;
  float s1=0.f, s2=0.f;
  for (int i=threadIdx.x;i<1520;i+=256) s1 += (float)Zf[(long)b*1520+i]*fc1w[i];
  for (int i=threadIdx.x;i<1000;i+=256) s2 += (float)Yf[(long)b*1000+i]*fc2w[i];
  __shared__ float r1[256], r2[256];
  r1[threadIdx.x]=s1; r2[threadIdx.x]=s2; __syncthreads();
  for (int d=128; d>0; d>>=1){
    if (threadIdx.x<d){ r1[threadIdx.x]+=r1[threadIdx.x+d]; r2[threadIdx.x]+=r2[threadIdx.x+d]; }
    __syncthreads();
  }
  if (threadIdx.x==0){
    float res = (r1[0]+fc1b[0])*(r2[0]+fc2b[0]);
    out[b] = fsig(res);
  }
}

// ---------------- launch ----------------
extern "C" void kernel_launch(void* const* d_in, const int* in_sizes, int n_in,
                              void* d_out, int out_size, void* d_ws, size_t ws_size,
                              hipStream_t stream) {
  const float* x    = (const float*)d_in[0];
  const int*   ei   = (const int*)d_in[1];
  const float* ggcw = (const float*)d_in[2];
  const float* wih  = (const float*)d_in[3];
  const float* whh  = (const float*)d_in[4];
  const float* bih  = (const float*)d_in[5];
  const float* bhh  = (const float*)d_in[6];
  const float* c1w  = (const float*)d_in[7];
  const float* c1b  = (const float*)d_in[8];
  const float* bn1g = (const float*)d_in[9];
  const float* bn1b = (const float*)d_in[10];
  const float* c2w  = (const float*)d_in[11];
  const float* c2b  = (const float*)d_in[12];
  const float* bn2g = (const float*)d_in[13];
  const float* bn2b = (const float*)d_in[14];
  const float* fc1w = (const float*)d_in[15];
  const float* fc1b = (const float*)d_in[16];
  const float* fc2w = (const float*)d_in[17];
  const float* fc2b = (const float*)d_in[18];
  float* out = (float*)d_out;

  char* ws = (char*)d_ws;
  size_t HS = (size_t)NN*OUT*2;                       // 41,984,000 B per h buffer
  _Float16* h0 = (_Float16*)ws;
  _Float16* h1 = (_Float16*)(ws + HS);
  _Float16* h2 = (_Float16*)(ws + 2*HS);
  _Float16* Xt = h1;                                  // overlay: 512*304*224*2 = 69.7 MB
  char* aux = ws + 3*HS;
  float*    Wf = (float*)aux;    aux += (size_t)6*200*600*4;
  _Float16* Bp = (_Float16*)aux; aux += (size_t)6*6*13*224*16*2;   // 3.35 MB
  _Float16* Wp1 = (_Float16*)aux; aux += (size_t)21*64*32*2;
  int* deg    = (int*)aux;       aux += (size_t)NN*4;
  int* part   = (int*)aux;       aux += (size_t)NN*4;
  int* bsum   = (int*)aux;       aux += 256*4;
  int* rowptr = (int*)aux;       aux += (size_t)(NN+16)*4;
  int* cursor = (int*)aux;       aux += (size_t)NN*4;
  int* col    = (int*)aux;       aux += (size_t)NE*4;
  float* sums = (float*)aux;     aux += 512*4;        // 4 buffers of 128
  _Float16* z_c1  = (_Float16*)aux;
  _Float16* y_c1  = z_c1  + (size_t)512*50*301;
  _Float16* z_mp1 = y_c1  + (size_t)512*50*200;
  _Float16* y_mp1 = z_mp1 + (size_t)512*50*150;
  _Float16* z_c2  = y_mp1 + (size_t)512*50*99;
  _Float16* y_c2  = z_c2  + (size_t)512*20*152;
  _Float16* z_mp2 = y_c2  + (size_t)512*20*101;
  _Float16* y_mp2 = z_mp2 + (size_t)512*1520;

  // precompute
  pad16<<<NN*OUT/256, 256, 0, stream>>>(x, h0);
  fuse_w_kernel<<<(6*200*600+255)/256, 256, 0, stream>>>(ggcw, wih, Wf);
  pack_b32<<<6*6*13*224*16/256, 256, 0, stream>>>(Wf, whh, Bp);
  pack_w1<<<(21*64*32+255)/256, 256, 0, stream>>>(c1w, Wp1);
  zero_f32<<<2, 256, 0, stream>>>(sums, 512);         // all 4 BN sum buffers, once
  // CSR (hierarchical scan)
  zero_i32<<<(NN+255)/256, 256, 0, stream>>>(deg, NN);
  count_deg<<<NE/256, 256, 0, stream>>>(ei, deg);
  scan_block<<<NN/512, 512, 0, stream>>>(deg, part, bsum);
  scan_bsum<<<1, 256, 0, stream>>>(bsum, NN/512);
  scan_add<<<(NN+255)/256, 256, 0, stream>>>(part, bsum, rowptr, cursor);
  fill_csr<<<NE/256, 256, 0, stream>>>(ei, cursor, col);

  // GGC layers (split: gather then GRU)
  _Float16* cur = h0; _Float16* other = h2;
  for (int i=0;i<LAYERS;i++){
    gather16<<<NN*25/256, 256, 0, stream>>>(cur, rowptr, col, h1);
    gru_mfma2<<<NN/64, 448, 0, stream>>>(h1, cur, Bp + (size_t)i*6*13*224*16,
                                         bih, bhh, other);
    _Float16* t = cur; cur = other; other = t;
  }
  // cur == h0 (final hidden, fp16); h1/h2 free -> Xt overlay

  // head
  build_xt<<<dim3(7, 10, BATCH), 256, 0, stream>>>(cur, x, Xt);
  conv1_both<<<4608, 256, 0, stream>>>(Xt, Wp1, c1b, z_c1, y_c1);

  bn_stats2<<<dim3(50,16,2), 256, 0, stream>>>(z_c1, y_c1, 50, 301, 200, sums, sums+128);
  bn_act_pool2<<<dim3((512*50*150+255)/256, 1, 2), 256, 0, stream>>>(z_c1, y_c1,
      sums, sums+128, bn1g, bn1b, 1.f/(512.f*301.f), 1.f/(512.f*200.f),
      50, 301, 200, 150, 99, 3, 1, z_mp1, y_mp1);

  conv2_both<<<dim3(BATCH, 2), 256, 0, stream>>>(z_mp1, y_mp1, c2w, c2b, z_c2, y_c2);

  bn_stats2<<<dim3(20,16,2), 256, 0, stream>>>(z_c2, y_c2, 20, 152, 101, sums+256, sums+384);
  bn_act_pool2<<<dim3((512*20*76+255)/256, 1, 2), 256, 0, stream>>>(z_c2, y_c2,
      sums+256, sums+384, bn2g, bn2b, 1.f/(512.f*152.f), 1.f/(512.f*101.f),
      20, 152, 101, 76, 50, 2, 0, z_mp2, y_mp2);

  final_kernel<<<BATCH, 256, 0, stream>>>(z_mp2, y_mp2, fc1w, fc1b, fc2w, fc2b, out);
}